// Round 7
// baseline (2719.417 us; speedup 1.0000x reference)
//
#include <hip/hip_runtime.h>
#include <hip/hip_bf16.h>

// ---------------------------------------------------------------------------
// SynthesisBlock (StyleGAN2): B=16, CIN=COUT=512, 32x32 -> 64x64.
// Inputs fp32 (runtime-verified via k_detect flag). Output fp32 (reference
// output dtype). Internal compute bf16 MFMA (threshold 2%*max|ref| admits it).
//
// R1: epilogue unrolled -> accumulator in registers (was scratch; 4.3x).
// R2: staging via global_load_lds width=16 (HBM->LDS DMA), linear LDS.
// R3: explicit LDS double-buffer -> NULL (confirms m99/m100/m131).
// R4/R5: T1 XCD swizzle of blockIdx.x -> FETCH -20%, +7%.
// R6: two K=32 blocks per barrier round (barriers halved) -> +13%, matched.
// R7: drop LDS from k_gemm ENTIRELY (m169 / Common-mistake #7: operands are
//     cache-resident -- xT 2MB/XCD L2, W slab 1.2MB/XCD L2, act0m 64MB L3 --
//     and NHWC means MFMA fragments map directly to global). Each wave
//     global_load_dwordx4's its fragments straight into registers: per K=32
//     step 8 independent loads + 16 MFMA, K fully unrolled so the compiler
//     deep-pipelines. Removes both per-phase barriers (vmcnt/lgkm drains),
//     all LDS port traffic (96KB/block-phase), and 3.78e7 conflict cycles.
// ---------------------------------------------------------------------------

typedef __attribute__((ext_vector_type(8))) short short8;
typedef __attribute__((ext_vector_type(4))) float floatx4;

__device__ __forceinline__ float bf2f(__hip_bfloat16 v){ return __bfloat162float(v); }
__device__ __forceinline__ __hip_bfloat16 f2bf(float v){ return __float2bfloat16(v); }

// adaptive input load: flag==1 -> fp32, else bf16
__device__ __forceinline__ float ldin(const void* p, size_t i, int f32){
  return f32 ? ((const float*)p)[i] : bf2f(((const __hip_bfloat16*)p)[i]);
}

// ---------------- dtype detector ----------------
__global__ void k_detect(const void* __restrict__ x, int* __restrict__ flag){
  __shared__ int cnt;
  if (threadIdx.x == 0) cnt = 0;
  __syncthreads();
  const __hip_bfloat16* xb = (const __hip_bfloat16*)x;
  int c = 0;
  for (int i = threadIdx.x; i < 4096; i += 256){
    float v = bf2f(xb[i]);
    if (!(fabsf(v) < 1e6f)) c++;       // catches NaN too (comparison false)
  }
  atomicAdd(&cnt, c);
  __syncthreads();
  if (threadIdx.x == 0) *flag = (cnt > 8) ? 1 : 0;
}

// ---------------- misc input -> fp32 conversion (+ zbuf zero-fill) ---------
__global__ void k_misc(const void* __restrict__ nc0, const void* __restrict__ nc1,
                       const void* __restrict__ b0,  const void* __restrict__ b1,
                       const void* __restrict__ ns0, const void* __restrict__ ns1,
                       const int* __restrict__ flag,
                       float* __restrict__ nf0, float* __restrict__ nf1,
                       float* __restrict__ b0f, float* __restrict__ b1f,
                       float* __restrict__ scf, float* __restrict__ zbuf){
  const int f32 = *flag;
  int i = blockIdx.x*256 + threadIdx.x;
  if (i < 4096)       nf0[i]      = ldin(nc0, i, f32);
  else if (i < 8192)  nf1[i-4096] = ldin(nc1, i-4096, f32);
  else if (i < 8704)  b0f[i-8192] = ldin(b0, i-8192, f32);
  else if (i < 9216)  b1f[i-8704] = ldin(b1, i-8704, f32);
  else if (i == 9216) scf[0]      = ldin(ns0, 0, f32);
  else if (i == 9217) scf[1]      = ldin(ns1, 0, f32);
  else if (i >= 9232 && i < 9744) zbuf[i-9232] = 0.0f;   // 2 KB zero guard
}

// ---------------- small prep kernels ----------------

__global__ void k_wsum(const void* __restrict__ w0, const void* __restrict__ w1,
                       const int* __restrict__ flag,
                       float* __restrict__ wsum0, float* __restrict__ wsum1){
  const int f32 = *flag;
  int idx = blockIdx.x*256 + threadIdx.x;           // oc*512+ci, 262144 total
  float a = 0.f, b = 0.f;
  #pragma unroll
  for(int t=0;t<9;t++){
    float v0 = ldin(w0, (size_t)idx*9+t, f32); a += v0*v0;
    float v1 = ldin(w1, (size_t)idx*9+t, f32); b += v1*v1;
  }
  wsum0[idx] = a; wsum1[idx] = b;
}

__global__ void k_styles(const void* __restrict__ lat2,
                         const void* __restrict__ aw0, const void* __restrict__ ab0,
                         const void* __restrict__ aw1, const void* __restrict__ ab1,
                         const int* __restrict__ flag,
                         float* __restrict__ s0, float* __restrict__ s1){
  const int f32 = *flag;
  int idx = blockIdx.x*256 + threadIdx.x;           // b*512+o, 8192 total
  if (idx >= 16*512) return;
  int b = idx>>9, o = idx&511;
  float a0 = 0.f, a1 = 0.f;
  for(int i=0;i<512;i++){
    a0 += ldin(lat2, (size_t)b*1024 + i,       f32) * ldin(aw0, (size_t)o*512+i, f32);
    a1 += ldin(lat2, (size_t)b*1024 + 512 + i, f32) * ldin(aw1, (size_t)o*512+i, f32);
  }
  const float inv = 0.04419417382415922f;           // 1/sqrt(512)
  s0[idx] = a0*inv + ldin(ab0, o, f32);
  s1[idx] = a1*inv + ldin(ab1, o, f32);
}

__global__ void k_demod(const float* __restrict__ s0, const float* __restrict__ s1,
                        const float* __restrict__ wsum0, const float* __restrict__ wsum1,
                        float* __restrict__ d0, float* __restrict__ d1){
  int idx = blockIdx.x*256 + threadIdx.x;           // b*512+o, 8192 total
  if (idx >= 16*512) return;
  int b = idx>>9, o = idx&511;
  float a0 = 0.f, a1 = 0.f;
  for(int i=0;i<512;i++){
    float t0 = s0[b*512+i]; a0 += t0*t0*wsum0[o*512+i];
    float t1 = s1[b*512+i]; a1 += t1*t1*wsum1[o*512+i];
  }
  d0[idx] = rsqrtf(a0 + 1e-8f);
  d1[idx] = rsqrtf(a1 + 1e-8f);
}

// NCHW -> NHWC transpose (adaptive input dtype)
__global__ void k_xprep(const void* __restrict__ x, const int* __restrict__ flag,
                        __hip_bfloat16* __restrict__ xT){
  const int f32 = *flag;
  int tid = blockIdx.x*256 + threadIdx.x;           // ((b*32+y)*32+xx)*512+ci
  int ci = tid&511; int r = tid>>9;
  int xx = r&31; r >>= 5; int yy = r&31; int b = r>>5;
  xT[tid] = f2bf(ldin(x, (size_t)(((b*512+ci)*32+yy)*32+xx), f32));
}

// in-place modulation: xT *= s0[b,ci]  (run AFTER the skip GEMM reads xT)
__global__ void k_xmod(__hip_bfloat16* __restrict__ xT,
                       const float* __restrict__ s0){
  int tid = blockIdx.x*256 + threadIdx.x;
  int ci = tid&511; int b = tid>>19;
  xT[tid] = f2bf(bf2f(xT[tid]) * s0[b*512+ci]);
}

// conv0: combined (flip(w0) then 4-tap FIR) kernels, per output-parity class.
__global__ void k_w0prep(const void* __restrict__ w0, const int* __restrict__ flag,
                         __hip_bfloat16* __restrict__ W0p){
  const int f32 = *flag;
  int idx = blockIdx.x*256 + threadIdx.x;           // oc*512+ci
  int oc = idx>>9, ci = idx&511;
  const float g[4] = {0.25f, 0.75f, 0.75f, 0.25f};  // [1,3,3,1]/8 * 2 per axis
  float K2[6][6] = {};
  #pragma unroll
  for(int ty=0;ty<3;ty++)
    #pragma unroll
    for(int tx=0;tx<3;tx++){
      float w = ldin(w0, (size_t)idx*9 + (2-ty)*3 + (2-tx), f32);
      #pragma unroll
      for(int qy=0;qy<4;qy++)
        #pragma unroll
        for(int qx=0;qx<4;qx++)
          K2[qy+ty][qx+tx] += g[qy]*g[qx]*w;
    }
  #pragma unroll
  for(int Py=0;Py<2;Py++)
    #pragma unroll
    for(int Px=0;Px<2;Px++){
      int cls = Py*2+Px;
      #pragma unroll
      for(int jy=0;jy<3;jy++)
        #pragma unroll
        for(int jx=0;jx<3;jx++){
          int sy = (1-Py) + 2*jy, sx = (1-Px) + 2*jx;
          W0p[((size_t)(cls*9 + jy*3+jx)*512 + oc)*512 + ci] = f2bf(K2[sy][sx]);
        }
    }
}

// w1 -> [tap][oc][ci]; skip weight scaled by sqrt(.5)/sqrt(512) = 1/32.
__global__ void k_w1prep(const void* __restrict__ w1, const void* __restrict__ skw,
                         const int* __restrict__ flag,
                         __hip_bfloat16* __restrict__ w1T,
                         __hip_bfloat16* __restrict__ wskipT){
  const int f32 = *flag;
  int idx = blockIdx.x*256 + threadIdx.x;           // oc*512+ci
  int oc = idx>>9, ci = idx&511;
  #pragma unroll
  for(int t=0;t<9;t++)
    w1T[((size_t)t*512 + oc)*512 + ci] = f2bf(ldin(w1, (size_t)idx*9+t, f32));
  wskipT[idx] = f2bf(ldin(skw, idx, f32) * 0.03125f);
}

// ---------------- implicit-GEMM conv kernel (LDS-free) ----------------
// A: NHWC [16,H,H,512] bf16. Weights: [cls][TAPS][512 oc][512 ci] bf16.
// Block tile 128(pixels) x 128(oc), 4 waves each computing 64x64 via
// 4x4 mfma_f32_16x16x32_bf16 tiles.
// Fragments load DIRECTLY from global (L2/L3-resident operands) into regs:
// lane reads short8 at row (.. + lm)*512 + (lane>>4)*8 + kk -- NHWC k-major
// matches the MFMA A/B fragment layout exactly. No LDS, no barriers.
// Boundary taps: per-lane pointer select to the zeroed guard buffer.
// blockIdx.x is XCD-swizzled (T1): XCD k owns a contiguous M-tile range.
// MODE 0: skip 1x1 -> tlow NHWC bf16.  MODE 1: conv0 parity class -> act0m
// NHWC bf16.  MODE 2: conv1 -> +upsampled skip -> d_out NCHW fp32.
template<int TAPS, int MODE, int H>
__launch_bounds__(256,4)
__global__ void k_gemm(const __hip_bfloat16* __restrict__ Ain,
                       const __hip_bfloat16* __restrict__ Wt,
                       const float* __restrict__ dvec,
                       const float* __restrict__ noise,
                       const float* __restrict__ nscal,
                       const float* __restrict__ bias,
                       const float* __restrict__ s1,
                       const __hip_bfloat16* __restrict__ tlow,
                       const __hip_bfloat16* __restrict__ zbuf,
                       void* __restrict__ Outv){
  constexpr int LOGH = (H==32)?5:6;
  const int t = threadIdx.x;
  // T1 XCD swizzle (bijective; gridDim.x % 8 == 0 for all launches here).
  const int mtile = ((blockIdx.x & 7) * (gridDim.x >> 3)) + (blockIdx.x >> 3);
  const int Mbase = mtile*128;
  const int Nbase = blockIdx.y*128;
  const int cls = blockIdx.z;
  const __hip_bfloat16* Wslab = Wt + (size_t)cls * TAPS * 512 * 512;

  const int wave = t>>6, lane = t&63;
  const int wm = (wave>>1)*64, wn = (wave&1)*64;
  const int lm = lane&15;
  const int lkq = (lane>>4)*8;       // k sub-offset within fragment (shorts)

  floatx4 acc[4][4];
  #pragma unroll
  for(int i=0;i<4;i++)
    #pragma unroll
    for(int j=0;j<4;j++)
      #pragma unroll
      for(int r=0;r<4;r++) acc[i][j][r] = 0.0f;

  // per-fragment pixel decomposition (per-lane; py/b uniform within a frag)
  int bI[4], pyI[4], pxI[4];
  #pragma unroll
  for(int i=0;i<4;i++){
    const int m = Mbase + wm + i*16 + lm;
    bI[i]  = m >> (2*LOGH);
    pyI[i] = (m >> LOGH) & (H-1);
    pxI[i] = m & (H-1);
  }
  const __hip_bfloat16* pB[4];
  #pragma unroll
  for(int j=0;j<4;j++)
    pB[j] = Wslab + (((Nbase + wn + j*16 + lm) << 9) + lkq);

  #pragma unroll 1
  for(int tap=0; tap<TAPS; ++tap){
    const int dy = (TAPS==1)?0:(tap/3 - 1);
    const int dx = (TAPS==1)?0:(tap%3 - 1);
    // per-lane A fragment pointers; out-of-bounds rows -> zero guard
    const __hip_bfloat16* pA[4];
    #pragma unroll
    for(int i=0;i<4;i++){
      const int iy = pyI[i] + dy, ix = pxI[i] + dx;
      const bool v = ((unsigned)iy < (unsigned)H) && ((unsigned)ix < (unsigned)H);
      pA[i] = v ? (Ain + ((((size_t)(bI[i]*H + iy)*H + ix) << 9) + lkq))
                : (zbuf + lkq);
    }
    const __hip_bfloat16* wtap = (TAPS==1) ? nullptr : (const __hip_bfloat16*)0;
    (void)wtap;
    const size_t tof = (size_t)tap * 262144;   // tap stride in B (shorts)

    // K loop fully unrolled: 16 x (8 independent loads + 16 MFMA) straight-
    // line; compiler pipelines loads across iterations (m97-style).
    #pragma unroll
    for(int kk=0; kk<512; kk+=32){
      short8 a[4], bb[4];
      #pragma unroll
      for(int i=0;i<4;i++) a[i]  = *(const short8*)(pA[i] + kk);
      #pragma unroll
      for(int j=0;j<4;j++) bb[j] = *(const short8*)(pB[j] + tof + kk);
      #pragma unroll
      for(int i=0;i<4;i++)
        #pragma unroll
        for(int j=0;j<4;j++)
          acc[i][j] = __builtin_amdgcn_mfma_f32_16x16x32_bf16(a[i], bb[j], acc[i][j], 0,0,0);
    }
  }

  // ---------------- epilogue ----------------
  // FULLY UNROLLED (i,j): every acc[i][j] access must be compile-time
  // indexed or the whole accumulator array lives in scratch (rule #20).
  const float nsv = (MODE>=1) ? nscal[0] : 0.0f;
  #pragma unroll
  for(int i=0;i<4;i++){
    #pragma unroll
    for(int j=0;j<4;j++){
      const int mt = Mbase + wm + i*16 + (lane>>4)*4;
      const int n  = Nbase + wn + j*16 + lm;
      #pragma unroll
      for(int r=0;r<4;r++){
        const int m = mt + r;
        float val = acc[i][j][r];
        if constexpr (MODE==0){
          ((__hip_bfloat16*)Outv)[(size_t)m*512 + n] = f2bf(val);
        } else if constexpr (MODE==1){
          const int b = m>>10, uy = (m>>5)&31, ux = m&31;
          const int py = 2*uy + (cls>>1), px = 2*ux + (cls&1);
          val = val*dvec[b*512+n] + noise[py*64+px]*nsv + bias[n];
          val = fmaxf(val, 0.0f) * 1.4142135623730951f * s1[b*512+n];
          ((__hip_bfloat16*)Outv)[(size_t)((b*64+py)*64+px)*512 + n] = f2bf(val);
        } else {
          const int b = m>>12, py = (m>>6)&63, px = m&63;
          val = val*dvec[b*512+n] + noise[py*64+px]*nsv + bias[n];
          val = fmaxf(val, 0.0f);   // gain sqrt(2)*sqrt(0.5) == 1
          // on-the-fly 2-tap-per-axis upsample of the skip GEMM
          const int uy = py>>1, ay = py&1, ux2 = px>>1, ax = px&1;
          const int ry = uy - 1 + ay, rx = ux2 - 1 + ax;
          const float cy0 = ay ? 0.75f : 0.25f, cy1 = ay ? 0.25f : 0.75f;
          const float cx0 = ax ? 0.75f : 0.25f, cx1 = ax ? 0.25f : 0.75f;
          float yv = 0.0f;
          #pragma unroll
          for(int e=0;e<2;e++){
            const int yy = ry + e;
            if ((unsigned)yy >= 32u) continue;
            const float cy = e ? cy1 : cy0;
            #pragma unroll
            for(int f=0;f<2;f++){
              const int xx = rx + f;
              if ((unsigned)xx >= 32u) continue;
              const float cx = f ? cx1 : cx0;
              yv += cy*cx*bf2f(tlow[(size_t)((b*32+yy)*32+xx)*512 + n]);
            }
          }
          val += yv;
          ((float*)Outv)[(size_t)((b*512 + n)*64 + py)*64 + px] = val;  // fp32 out
        }
      }
    }
  }
}

// ---------------- launch ----------------

extern "C" void kernel_launch(void* const* d_in, const int* in_sizes, int n_in,
                              void* d_out, int out_size, void* d_ws, size_t ws_size,
                              hipStream_t stream){
  (void)in_sizes; (void)n_in; (void)out_size; (void)ws_size;
  const void* x    = d_in[0];
  // d_in[1] = latent1 (unused by reference)
  const void* lat2 = d_in[2];
  const void* aw0  = d_in[3];
  const void* ab0  = d_in[4];
  const void* w0   = d_in[5];
  const void* b0   = d_in[6];
  const void* nc0  = d_in[7];
  const void* ns0  = d_in[8];
  const void* aw1  = d_in[9];
  const void* ab1  = d_in[10];
  const void* w1   = d_in[11];
  const void* b1   = d_in[12];
  const void* nc1  = d_in[13];
  const void* ns1  = d_in[14];
  const void* skw  = d_in[15];

  // -------- workspace layout: ~119.2 MB total --------
  char* p = (char*)d_ws;
  float* s0v   = (float*)p; p += 16*512*4;                          // 32 KB
  float* s1v   = (float*)p; p += 16*512*4;
  float* d0v   = (float*)p; p += 16*512*4;
  float* d1v   = (float*)p; p += 16*512*4;
  float* nf0   = (float*)p; p += 4096*4;                            // 16 KB
  float* nf1   = (float*)p; p += 4096*4;
  float* b0f   = (float*)p; p += 512*4;
  float* b1f   = (float*)p; p += 512*4;
  float* scf   = (float*)p; p += 16;                                // ns0,ns1
  int*   flag  = (int*)p;   p += 16;
  float* zbuf  = (float*)p; p += 512*4;                             // 2 KB zeros
  __hip_bfloat16* w1T    = (__hip_bfloat16*)p; p += (size_t)9*512*512*2;   // 4.5 MB
  __hip_bfloat16* wskipT = (__hip_bfloat16*)p; p += (size_t)512*512*2;     // 0.5 MB
  __hip_bfloat16* tlow   = (__hip_bfloat16*)p; p += (size_t)16*32*32*512*2;// 16 MB
  __hip_bfloat16* xT     = (__hip_bfloat16*)p; p += (size_t)16*32*32*512*2;// 16 MB
  __hip_bfloat16* W0p    = (__hip_bfloat16*)p; p += (size_t)4*9*512*512*2; // 18 MB
  __hip_bfloat16* act0m  = (__hip_bfloat16*)p; p += (size_t)16*64*64*512*2;// 64 MB
  // wsum0/wsum1 (2 MB) overlaid on act0m's base: dead after k_demod, which
  // stream-orders before conv0's first write to act0m.
  float* wsum0 = (float*)act0m;
  float* wsum1 = (float*)act0m + 512*512;

  const __hip_bfloat16* zb = (const __hip_bfloat16*)zbuf;

  k_detect<<<   1, 256, 0, stream>>>(x, flag);
  k_misc  <<<  39, 256, 0, stream>>>(nc0, nc1, b0, b1, ns0, ns1, flag,
                                     nf0, nf1, b0f, b1f, scf, zbuf);
  k_wsum  <<<1024, 256, 0, stream>>>(w0, w1, flag, wsum0, wsum1);
  k_styles<<<  32, 256, 0, stream>>>(lat2, aw0, ab0, aw1, ab1, flag, s0v, s1v);
  k_demod <<<  32, 256, 0, stream>>>(s0v, s1v, wsum0, wsum1, d0v, d1v);
  k_xprep <<<32768,256, 0, stream>>>(x, flag, xT);
  k_w0prep<<<1024, 256, 0, stream>>>(w0, flag, W0p);
  k_w1prep<<<1024, 256, 0, stream>>>(w1, skw, flag, w1T, wskipT);

  // skip 1x1 on low-res grid (reads UNMODULATED xT)
  k_gemm<1,0,32><<<dim3(128,4,1), 256, 0, stream>>>(
      xT, wskipT, nullptr, nullptr, nullptr, nullptr, nullptr, nullptr, zb, tlow);
  // modulate xT in place for conv0
  k_xmod  <<<32768,256, 0, stream>>>(xT, s0v);
  // conv0 (4 parity classes via blockIdx.z)
  k_gemm<9,1,32><<<dim3(128,4,4), 256, 0, stream>>>(
      xT, W0p, d0v, nf0, scf, b0f, s1v, nullptr, zb, act0m);
  // conv1 + skip add -> NCHW fp32 output
  k_gemm<9,2,64><<<dim3(512,4,1), 256, 0, stream>>>(
      act0m, w1T, d1v, nf1, scf+1, b1f, nullptr, tlow, zb, d_out);
}

// Round 9
// 1367.472 us; speedup vs baseline: 1.9886x; 1.9886x over previous
//
#include <hip/hip_runtime.h>
#include <hip/hip_bf16.h>

// ---------------------------------------------------------------------------
// SynthesisBlock (StyleGAN2): B=16, CIN=COUT=512, 32x32 -> 64x64.
// Inputs fp32 (runtime-verified via k_detect flag). Output fp32 (reference
// output dtype). Internal compute bf16 MFMA (threshold 2%*max|ref| admits it).
//
// R1: epilogue unrolled -> accumulator in registers (was scratch; 4.3x).
// R2: staging via global_load_lds width=16 (HBM->LDS DMA), linear LDS.
// R3: explicit LDS double-buffer -> NULL (confirms m99/m100/m131).
// R4/R5: T1 XCD swizzle of blockIdx.x -> FETCH -20%, +7%.
// R6: two K=32 blocks per barrier round (barriers halved) -> +13%, matched.
// R7: LDS-free direct-from-L2 fragments -> 2.1x REGRESSION (latency-bound:
//     60 VGPRs can't hold enough in-flight loads; LDS's DMA queue is the
//     latency decoupler). Reverted. Useful finding: all 3.78e7 conflict
//     cycles are the GEMM ds_reads; LDS port is R6's tightest resource.
// R8: R6 + LDS XOR-swizzle done the rule-#21 way (linear DMA dest +
//     inverse-swizzled per-lane GLOBAL source + swizzled read):
//     granule k2 -> k2 ^ ((row>>1)&3)  (16B granules within 64B rows).
//     Staging source offset: ((l&3)^((l>>3)&3))*8 shorts; read offset:
//     ((lane>>4)^((lane>>1)&3))*8. 16-lane read groups now cover all 32
//     banks 2-way (free, m136) instead of 8 banks 8-way.
// R9: resubmit of R8 (broker infra failed twice, as in R4; swizzle algebra
//     re-audited: involution + bank coverage + guard bounds all check out).
// ---------------------------------------------------------------------------

typedef __attribute__((ext_vector_type(8))) short short8;
typedef __attribute__((ext_vector_type(4))) float floatx4;

__device__ __forceinline__ float bf2f(__hip_bfloat16 v){ return __bfloat162float(v); }
__device__ __forceinline__ __hip_bfloat16 f2bf(float v){ return __float2bfloat16(v); }

// direct HBM->LDS 16B per lane. LDS dest: wave-uniform base + lane*16B.
// Global src: per-lane address.
__device__ __forceinline__ void glds16(const __hip_bfloat16* g, const short* l){
  __builtin_amdgcn_global_load_lds(
      (const __attribute__((address_space(1))) void*)g,
      (__attribute__((address_space(3))) void*)l,
      16, 0, 0);
}

// adaptive input load: flag==1 -> fp32, else bf16
__device__ __forceinline__ float ldin(const void* p, size_t i, int f32){
  return f32 ? ((const float*)p)[i] : bf2f(((const __hip_bfloat16*)p)[i]);
}

// ---------------- dtype detector ----------------
__global__ void k_detect(const void* __restrict__ x, int* __restrict__ flag){
  __shared__ int cnt;
  if (threadIdx.x == 0) cnt = 0;
  __syncthreads();
  const __hip_bfloat16* xb = (const __hip_bfloat16*)x;
  int c = 0;
  for (int i = threadIdx.x; i < 4096; i += 256){
    float v = bf2f(xb[i]);
    if (!(fabsf(v) < 1e6f)) c++;       // catches NaN too (comparison false)
  }
  atomicAdd(&cnt, c);
  __syncthreads();
  if (threadIdx.x == 0) *flag = (cnt > 8) ? 1 : 0;
}

// ---------------- misc input -> fp32 conversion (+ zbuf zero-fill) ---------
__global__ void k_misc(const void* __restrict__ nc0, const void* __restrict__ nc1,
                       const void* __restrict__ b0,  const void* __restrict__ b1,
                       const void* __restrict__ ns0, const void* __restrict__ ns1,
                       const int* __restrict__ flag,
                       float* __restrict__ nf0, float* __restrict__ nf1,
                       float* __restrict__ b0f, float* __restrict__ b1f,
                       float* __restrict__ scf, float* __restrict__ zbuf){
  const int f32 = *flag;
  int i = blockIdx.x*256 + threadIdx.x;
  if (i < 4096)       nf0[i]      = ldin(nc0, i, f32);
  else if (i < 8192)  nf1[i-4096] = ldin(nc1, i-4096, f32);
  else if (i < 8704)  b0f[i-8192] = ldin(b0, i-8192, f32);
  else if (i < 9216)  b1f[i-8704] = ldin(b1, i-8704, f32);
  else if (i == 9216) scf[0]      = ldin(ns0, 0, f32);
  else if (i == 9217) scf[1]      = ldin(ns1, 0, f32);
  else if (i >= 9232 && i < 9744) zbuf[i-9232] = 0.0f;   // 2 KB zero guard
}

// ---------------- small prep kernels ----------------

__global__ void k_wsum(const void* __restrict__ w0, const void* __restrict__ w1,
                       const int* __restrict__ flag,
                       float* __restrict__ wsum0, float* __restrict__ wsum1){
  const int f32 = *flag;
  int idx = blockIdx.x*256 + threadIdx.x;           // oc*512+ci, 262144 total
  float a = 0.f, b = 0.f;
  #pragma unroll
  for(int t=0;t<9;t++){
    float v0 = ldin(w0, (size_t)idx*9+t, f32); a += v0*v0;
    float v1 = ldin(w1, (size_t)idx*9+t, f32); b += v1*v1;
  }
  wsum0[idx] = a; wsum1[idx] = b;
}

__global__ void k_styles(const void* __restrict__ lat2,
                         const void* __restrict__ aw0, const void* __restrict__ ab0,
                         const void* __restrict__ aw1, const void* __restrict__ ab1,
                         const int* __restrict__ flag,
                         float* __restrict__ s0, float* __restrict__ s1){
  const int f32 = *flag;
  int idx = blockIdx.x*256 + threadIdx.x;           // b*512+o, 8192 total
  if (idx >= 16*512) return;
  int b = idx>>9, o = idx&511;
  float a0 = 0.f, a1 = 0.f;
  for(int i=0;i<512;i++){
    a0 += ldin(lat2, (size_t)b*1024 + i,       f32) * ldin(aw0, (size_t)o*512+i, f32);
    a1 += ldin(lat2, (size_t)b*1024 + 512 + i, f32) * ldin(aw1, (size_t)o*512+i, f32);
  }
  const float inv = 0.04419417382415922f;           // 1/sqrt(512)
  s0[idx] = a0*inv + ldin(ab0, o, f32);
  s1[idx] = a1*inv + ldin(ab1, o, f32);
}

__global__ void k_demod(const float* __restrict__ s0, const float* __restrict__ s1,
                        const float* __restrict__ wsum0, const float* __restrict__ wsum1,
                        float* __restrict__ d0, float* __restrict__ d1){
  int idx = blockIdx.x*256 + threadIdx.x;           // b*512+o, 8192 total
  if (idx >= 16*512) return;
  int b = idx>>9, o = idx&511;
  float a0 = 0.f, a1 = 0.f;
  for(int i=0;i<512;i++){
    float t0 = s0[b*512+i]; a0 += t0*t0*wsum0[o*512+i];
    float t1 = s1[b*512+i]; a1 += t1*t1*wsum1[o*512+i];
  }
  d0[idx] = rsqrtf(a0 + 1e-8f);
  d1[idx] = rsqrtf(a1 + 1e-8f);
}

// NCHW -> NHWC transpose (adaptive input dtype)
__global__ void k_xprep(const void* __restrict__ x, const int* __restrict__ flag,
                        __hip_bfloat16* __restrict__ xT){
  const int f32 = *flag;
  int tid = blockIdx.x*256 + threadIdx.x;           // ((b*32+y)*32+xx)*512+ci
  int ci = tid&511; int r = tid>>9;
  int xx = r&31; r >>= 5; int yy = r&31; int b = r>>5;
  xT[tid] = f2bf(ldin(x, (size_t)(((b*512+ci)*32+yy)*32+xx), f32));
}

// in-place modulation: xT *= s0[b,ci]  (run AFTER the skip GEMM reads xT)
__global__ void k_xmod(__hip_bfloat16* __restrict__ xT,
                       const float* __restrict__ s0){
  int tid = blockIdx.x*256 + threadIdx.x;
  int ci = tid&511; int b = tid>>19;
  xT[tid] = f2bf(bf2f(xT[tid]) * s0[b*512+ci]);
}

// conv0: combined (flip(w0) then 4-tap FIR) kernels, per output-parity class.
__global__ void k_w0prep(const void* __restrict__ w0, const int* __restrict__ flag,
                         __hip_bfloat16* __restrict__ W0p){
  const int f32 = *flag;
  int idx = blockIdx.x*256 + threadIdx.x;           // oc*512+ci
  int oc = idx>>9, ci = idx&511;
  const float g[4] = {0.25f, 0.75f, 0.75f, 0.25f};  // [1,3,3,1]/8 * 2 per axis
  float K2[6][6] = {};
  #pragma unroll
  for(int ty=0;ty<3;ty++)
    #pragma unroll
    for(int tx=0;tx<3;tx++){
      float w = ldin(w0, (size_t)idx*9 + (2-ty)*3 + (2-tx), f32);
      #pragma unroll
      for(int qy=0;qy<4;qy++)
        #pragma unroll
        for(int qx=0;qx<4;qx++)
          K2[qy+ty][qx+tx] += g[qy]*g[qx]*w;
    }
  #pragma unroll
  for(int Py=0;Py<2;Py++)
    #pragma unroll
    for(int Px=0;Px<2;Px++){
      int cls = Py*2+Px;
      #pragma unroll
      for(int jy=0;jy<3;jy++)
        #pragma unroll
        for(int jx=0;jx<3;jx++){
          int sy = (1-Py) + 2*jy, sx = (1-Px) + 2*jx;
          W0p[((size_t)(cls*9 + jy*3+jx)*512 + oc)*512 + ci] = f2bf(K2[sy][sx]);
        }
    }
}

// w1 -> [tap][oc][ci]; skip weight scaled by sqrt(.5)/sqrt(512) = 1/32.
__global__ void k_w1prep(const void* __restrict__ w1, const void* __restrict__ skw,
                         const int* __restrict__ flag,
                         __hip_bfloat16* __restrict__ w1T,
                         __hip_bfloat16* __restrict__ wskipT){
  const int f32 = *flag;
  int idx = blockIdx.x*256 + threadIdx.x;           // oc*512+ci
  int oc = idx>>9, ci = idx&511;
  #pragma unroll
  for(int t=0;t<9;t++)
    w1T[((size_t)t*512 + oc)*512 + ci] = f2bf(ldin(w1, (size_t)idx*9+t, f32));
  wskipT[idx] = f2bf(ldin(skw, idx, f32) * 0.03125f);
}

// ---------------- implicit-GEMM conv kernel ----------------
// A: NHWC [16,H,H,512] bf16. Weights: [cls][TAPS][512 oc][512 ci] bf16.
// Block tile 128(pixels) x 128(oc), 4 waves each computing 64x64 via
// 4x4 mfma_f32_16x16x32_bf16 tiles.
// Staging: global_load_lds width=16 into TWO K=32 blocks per barrier round
// (As[2]/Bs[2], each [128][32] shorts, 64B rows). Per phase: 8 glds16/thread,
// barrier (vmcnt drain), 2 x (8 ds_read_b128 + 16 MFMA)/wave, barrier.
// LDS XOR-swizzle (rule #21): LDS[row][k2] = G[row][k2 ^ ((row>>1)&3)]
// (16B granules). DMA dest stays LINEAR; the per-lane GLOBAL source applies
// the inverse permutation; ds_reads apply the same XOR. 16-lane read groups
// then cover all 32 banks 2-way (free) instead of 8 banks 8-way.
// blockIdx.x is XCD-swizzled (T1): XCD k owns a contiguous M-tile range.
// MODE 0: skip 1x1 -> tlow NHWC bf16.  MODE 1: conv0 parity class -> act0m
// NHWC bf16.  MODE 2: conv1 -> +upsampled skip -> d_out NCHW fp32.
template<int TAPS, int MODE, int H>
__launch_bounds__(256,4)
__global__ void k_gemm(const __hip_bfloat16* __restrict__ Ain,
                       const __hip_bfloat16* __restrict__ Wt,
                       const float* __restrict__ dvec,
                       const float* __restrict__ noise,
                       const float* __restrict__ nscal,
                       const float* __restrict__ bias,
                       const float* __restrict__ s1,
                       const __hip_bfloat16* __restrict__ tlow,
                       const __hip_bfloat16* __restrict__ zbuf,
                       void* __restrict__ Outv){
  constexpr int LOGH = (H==32)?5:6;
  __shared__ short As[2][128*32];
  __shared__ short Bs[2][128*32];
  const int t = threadIdx.x;
  // T1 XCD swizzle (bijective; gridDim.x % 8 == 0 for all launches here).
  const int mtile = ((blockIdx.x & 7) * (gridDim.x >> 3)) + (blockIdx.x >> 3);
  const int Mbase = mtile*128;
  const int Nbase = blockIdx.y*128;
  const int cls = blockIdx.z;
  const __hip_bfloat16* Wslab = Wt + (size_t)cls * TAPS * 512 * 512;

  const int wave = t>>6, lane = t&63;
  const int wm = (wave>>1)*64, wn = (wave&1)*64;
  const int lm = lane&15;
  // swizzled read offset: granule q=lane>>4 of row lm -> LDS granule q^s,
  // s = (row>>1)&3 = (lane>>1)&3 for row = wm + i*16 + lm (wm,16i = 0 mod 8)
  const int lksw = (((lane>>4) ^ ((lane>>1)&3)) << 3);

  // staging mapping (global_load_lds): chunk c -> LDS rows [c*16, c*16+16)
  const int rsub = lane>>2;          // 0..15 row-in-chunk
  // inverse-swizzled source granule: LDS granule k2=lane&3 of row rsub must
  // hold G granule k2^s, s = (row>>1)&3 = (lane>>3)&3 (chunk-independent:
  // row = c*16 + rsub and (c*16)>>1 is 0 mod 4)
  const int koff = (((lane&3) ^ ((lane>>3)&3)) << 3);  // k sub-offset (shorts)
  const int row0 = wave*16 + rsub;   // chunk `wave`   : rows 0..63
  const int row1 = row0 + 64;        // chunk `wave+4` : rows 64..127
  short* ldsA00 = As[0] + wave*512;  // wave-uniform LDS bases (1024B chunks)
  short* ldsA01 = As[0] + (wave+4)*512;
  short* ldsA10 = As[1] + wave*512;
  short* ldsA11 = As[1] + (wave+4)*512;
  short* ldsB00 = Bs[0] + wave*512;
  short* ldsB01 = Bs[0] + (wave+4)*512;
  short* ldsB10 = Bs[1] + wave*512;
  short* ldsB11 = Bs[1] + (wave+4)*512;

  floatx4 acc[4][4];
  #pragma unroll
  for(int i=0;i<4;i++)
    #pragma unroll
    for(int j=0;j<4;j++)
      #pragma unroll
      for(int r=0;r<4;r++) acc[i][j][r] = 0.0f;

  const int m0 = Mbase + row0, m1 = Mbase + row1;
  const int b0p = m0 >> (2*LOGH), b1p = m1 >> (2*LOGH);
  const int py0 = (m0 >> LOGH)&(H-1), py1 = (m1 >> LOGH)&(H-1);
  const int px0 = m0 & (H-1),        px1 = m1 & (H-1);

  #pragma unroll 1
  for(int tap=0; tap<TAPS; ++tap){
    const int dy = (TAPS==1)?0:(tap/3 - 1);
    const int dx = (TAPS==1)?0:(tap%3 - 1);
    const int iy0 = py0+dy, ix0 = px0+dx, iy1 = py1+dy, ix1 = px1+dx;
    const bool v0 = ((unsigned)iy0 < (unsigned)H) && ((unsigned)ix0 < (unsigned)H);
    const bool v1 = ((unsigned)iy1 < (unsigned)H) && ((unsigned)ix1 < (unsigned)H);
    // per-lane global sources; invalid rows read the zeroed guard buffer
    // (guard is 2 KB; koff<=24 + 448 advance + 32+8 read stays inside)
    const __hip_bfloat16* pA0 = v0 ? (Ain + ((((b0p*H + iy0)*H + ix0) << 9) + koff))
                                   : (zbuf + koff);
    const __hip_bfloat16* pA1 = v1 ? (Ain + ((((b1p*H + iy1)*H + ix1) << 9) + koff))
                                   : (zbuf + koff);
    const __hip_bfloat16* wt  = Wslab + (size_t)tap*512*512;
    const __hip_bfloat16* pB0 = wt + (Nbase + row0)*512 + koff;
    const __hip_bfloat16* pB1 = wt + (Nbase + row1)*512 + koff;

    #pragma unroll 1
    for(int kk=0; kk<512; kk+=64){
      // stage two K=32 blocks (this kk and kk+32) in one round
      glds16(pA0,      ldsA00);
      glds16(pA0 + 32, ldsA10);
      glds16(pA1,      ldsA01);
      glds16(pA1 + 32, ldsA11);
      glds16(pB0,      ldsB00);
      glds16(pB0 + 32, ldsB10);
      glds16(pB1,      ldsB01);
      glds16(pB1 + 32, ldsB11);
      __syncthreads();               // vmcnt drain: both blocks resident
      #pragma unroll
      for(int h=0; h<2; ++h){
        short8 af[4], bf[4];
        #pragma unroll
        for(int i=0;i<4;i++) af[i] = *(const short8*)&As[h][(wm + i*16 + lm)*32 + lksw];
        #pragma unroll
        for(int j=0;j<4;j++) bf[j] = *(const short8*)&Bs[h][(wn + j*16 + lm)*32 + lksw];
        #pragma unroll
        for(int i=0;i<4;i++)
          #pragma unroll
          for(int j=0;j<4;j++)
            acc[i][j] = __builtin_amdgcn_mfma_f32_16x16x32_bf16(af[i], bf[j], acc[i][j], 0,0,0);
      }
      __syncthreads();               // all reads done before next overwrite
      pA0 += 64; pA1 += 64; pB0 += 64; pB1 += 64;
    }
  }

  // ---------------- epilogue ----------------
  // FULLY UNROLLED (i,j): every acc[i][j] access must be compile-time
  // indexed or the whole accumulator array lives in scratch (rule #20).
  const float nsv = (MODE>=1) ? nscal[0] : 0.0f;
  #pragma unroll
  for(int i=0;i<4;i++){
    #pragma unroll
    for(int j=0;j<4;j++){
      const int mt = Mbase + wm + i*16 + ((lane>>4))*4;
      const int n  = Nbase + wn + j*16 + lm;
      #pragma unroll
      for(int r=0;r<4;r++){
        const int m = mt + r;
        float val = acc[i][j][r];
        if constexpr (MODE==0){
          ((__hip_bfloat16*)Outv)[(size_t)m*512 + n] = f2bf(val);
        } else if constexpr (MODE==1){
          const int b = m>>10, uy = (m>>5)&31, ux = m&31;
          const int py = 2*uy + (cls>>1), px = 2*ux + (cls&1);
          val = val*dvec[b*512+n] + noise[py*64+px]*nsv + bias[n];
          val = fmaxf(val, 0.0f) * 1.4142135623730951f * s1[b*512+n];
          ((__hip_bfloat16*)Outv)[(size_t)((b*64+py)*64+px)*512 + n] = f2bf(val);
        } else {
          const int b = m>>12, py = (m>>6)&63, px = m&63;
          val = val*dvec[b*512+n] + noise[py*64+px]*nsv + bias[n];
          val = fmaxf(val, 0.0f);   // gain sqrt(2)*sqrt(0.5) == 1
          // on-the-fly 2-tap-per-axis upsample of the skip GEMM
          const int uy = py>>1, ay = py&1, ux2 = px>>1, ax = px&1;
          const int ry = uy - 1 + ay, rx = ux2 - 1 + ax;
          const float cy0 = ay ? 0.75f : 0.25f, cy1 = ay ? 0.25f : 0.75f;
          const float cx0 = ax ? 0.75f : 0.25f, cx1 = ax ? 0.25f : 0.75f;
          float yv = 0.0f;
          #pragma unroll
          for(int e=0;e<2;e++){
            const int yy = ry + e;
            if ((unsigned)yy >= 32u) continue;
            const float cy = e ? cy1 : cy0;
            #pragma unroll
            for(int f=0;f<2;f++){
              const int xx = rx + f;
              if ((unsigned)xx >= 32u) continue;
              const float cx = f ? cx1 : cx0;
              yv += cy*cx*bf2f(tlow[(size_t)((b*32+yy)*32+xx)*512 + n]);
            }
          }
          val += yv;
          ((float*)Outv)[(size_t)((b*512 + n)*64 + py)*64 + px] = val;  // fp32 out
        }
      }
    }
  }
}

// ---------------- launch ----------------

extern "C" void kernel_launch(void* const* d_in, const int* in_sizes, int n_in,
                              void* d_out, int out_size, void* d_ws, size_t ws_size,
                              hipStream_t stream){
  (void)in_sizes; (void)n_in; (void)out_size; (void)ws_size;
  const void* x    = d_in[0];
  // d_in[1] = latent1 (unused by reference)
  const void* lat2 = d_in[2];
  const void* aw0  = d_in[3];
  const void* ab0  = d_in[4];
  const void* w0   = d_in[5];
  const void* b0   = d_in[6];
  const void* nc0  = d_in[7];
  const void* ns0  = d_in[8];
  const void* aw1  = d_in[9];
  const void* ab1  = d_in[10];
  const void* w1   = d_in[11];
  const void* b1   = d_in[12];
  const void* nc1  = d_in[13];
  const void* ns1  = d_in[14];
  const void* skw  = d_in[15];

  // -------- workspace layout: ~119.2 MB total --------
  char* p = (char*)d_ws;
  float* s0v   = (float*)p; p += 16*512*4;                          // 32 KB
  float* s1v   = (float*)p; p += 16*512*4;
  float* d0v   = (float*)p; p += 16*512*4;
  float* d1v   = (float*)p; p += 16*512*4;
  float* nf0   = (float*)p; p += 4096*4;                            // 16 KB
  float* nf1   = (float*)p; p += 4096*4;
  float* b0f   = (float*)p; p += 512*4;
  float* b1f   = (float*)p; p += 512*4;
  float* scf   = (float*)p; p += 16;                                // ns0,ns1
  int*   flag  = (int*)p;   p += 16;
  float* zbuf  = (float*)p; p += 512*4;                             // 2 KB zeros
  __hip_bfloat16* w1T    = (__hip_bfloat16*)p; p += (size_t)9*512*512*2;   // 4.5 MB
  __hip_bfloat16* wskipT = (__hip_bfloat16*)p; p += (size_t)512*512*2;     // 0.5 MB
  __hip_bfloat16* tlow   = (__hip_bfloat16*)p; p += (size_t)16*32*32*512*2;// 16 MB
  __hip_bfloat16* xT     = (__hip_bfloat16*)p; p += (size_t)16*32*32*512*2;// 16 MB
  __hip_bfloat16* W0p    = (__hip_bfloat16*)p; p += (size_t)4*9*512*512*2; // 18 MB
  __hip_bfloat16* act0m  = (__hip_bfloat16*)p; p += (size_t)16*64*64*512*2;// 64 MB
  // wsum0/wsum1 (2 MB) overlaid on act0m's base: dead after k_demod, which
  // stream-orders before conv0's first write to act0m.
  float* wsum0 = (float*)act0m;
  float* wsum1 = (float*)act0m + 512*512;

  const __hip_bfloat16* zb = (const __hip_bfloat16*)zbuf;

  k_detect<<<   1, 256, 0, stream>>>(x, flag);
  k_misc  <<<  39, 256, 0, stream>>>(nc0, nc1, b0, b1, ns0, ns1, flag,
                                     nf0, nf1, b0f, b1f, scf, zbuf);
  k_wsum  <<<1024, 256, 0, stream>>>(w0, w1, flag, wsum0, wsum1);
  k_styles<<<  32, 256, 0, stream>>>(lat2, aw0, ab0, aw1, ab1, flag, s0v, s1v);
  k_demod <<<  32, 256, 0, stream>>>(s0v, s1v, wsum0, wsum1, d0v, d1v);
  k_xprep <<<32768,256, 0, stream>>>(x, flag, xT);
  k_w0prep<<<1024, 256, 0, stream>>>(w0, flag, W0p);
  k_w1prep<<<1024, 256, 0, stream>>>(w1, skw, flag, w1T, wskipT);

  // skip 1x1 on low-res grid (reads UNMODULATED xT)
  k_gemm<1,0,32><<<dim3(128,4,1), 256, 0, stream>>>(
      xT, wskipT, nullptr, nullptr, nullptr, nullptr, nullptr, nullptr, zb, tlow);
  // modulate xT in place for conv0
  k_xmod  <<<32768,256, 0, stream>>>(xT, s0v);
  // conv0 (4 parity classes via blockIdx.z)
  k_gemm<9,1,32><<<dim3(128,4,4), 256, 0, stream>>>(
      xT, W0p, d0v, nf0, scf, b0f, s1v, nullptr, zb, act0m);
  // conv1 + skip add -> NCHW fp32 output
  k_gemm<9,2,64><<<dim3(512,4,1), 256, 0, stream>>>(
      act0m, w1T, d1v, nf1, scf+1, b1f, nullptr, tlow, zb, d_out);
}